// Round 3
// baseline (558.496 us; speedup 1.0000x reference)
//
#include <hip/hip_runtime.h>
#include <hip/hip_bf16.h>
#include <math.h>

#define B_ 16
#define S_ 4096
#define E_ 1024
#define H_ 512

#define BM 128
#define BN 128
#define BK 64
#define NCHUNK (E_ / BK)  // 16

typedef short bf16x8 __attribute__((ext_vector_type(8)));
typedef unsigned short u16x8 __attribute__((ext_vector_type(8)));
typedef float f32x4 __attribute__((ext_vector_type(4)));

__device__ inline unsigned short f2bf(float x) {
    __hip_bfloat16 h = __float2bfloat16(x);
    return *(unsigned short*)&h;
}

#define GLD16(g, l_) __builtin_amdgcn_global_load_lds(                     \
    (const __attribute__((address_space(1))) void*)(g),                    \
    (__attribute__((address_space(3))) void*)(l_), 16, 0, 0)

// Small prep (192 blocks):
//  blocks 0..63    : We -> WeTcB bf16, swizzled-chunk layout:
//                    WeTcB[c*32768 + n*64 + cp*8 + j] = We[k][n],
//                    k = c*64 + (cp ^ (n&7))*8 + j   (bank-conflict-free frags)
//  blocks 64..191  : dp[b][h] = dec[b,:].Wd[:,h] + bd[h] + be[h]
__global__ __launch_bounds__(256) void prep_kernel(
    const float* __restrict__ We, const float* __restrict__ dec,
    const float* __restrict__ Wd, const float* __restrict__ bd,
    const float* __restrict__ be, unsigned short* __restrict__ WeTcB,
    float* __restrict__ dp) {
    __shared__ float red[4][64];
    int bid = blockIdx.x, t = threadIdx.x;
    if (bid < 64) {
        int c = bid >> 2, n0t = (bid & 3) * 128;
#pragma unroll 4
        for (int it = 0; it < 32; ++it) {
            int o = it * 256 + t;
            int n_rel = o >> 6, within = o & 63;
            int cp = within >> 3, j = within & 7;
            int n = n0t + n_rel;
            int k = c * 64 + ((cp ^ (n & 7)) << 3) + j;
            WeTcB[c * 32768 + n * 64 + within] = f2bf(We[(size_t)k * H_ + n]);
        }
    } else {
        int id = bid - 64;
        int b = id >> 3, hc = id & 7;
        int h = hc * 64 + (t & 63);
        int ec = t >> 6;
        const float* dr = dec + b * E_ + ec * 256;
        const float* wp = Wd + (size_t)(ec * 256) * H_ + h;
        float acc = 0.f;
#pragma unroll 8
        for (int e = 0; e < 256; ++e) acc = fmaf(dr[e], wp[(size_t)e * H_], acc);
        red[ec][t & 63] = acc;
        __syncthreads();
        if (t < 64) {
            int hh = hc * 64 + t;
            dp[b * H_ + hh] = red[0][t] + red[1][t] + red[2][t] + red[3][t] + bd[hh] + be[hh];
        }
    }
}

// 128x128x64 GEMM, 4 waves (2m x 2n), acc 4x4 frags, fused fp32->bf16 A.
//   2 blocks/CU (65 KB LDS) -> 16 waves/CU: cross-block latency hiding replaces
//   deep in-block pipelining (short K=1024 means only 16 K-tiles; the 8-phase
//   256^2 schedule measured 13% MfmaUtil / 23% occupancy here).
//   Per K-tile (minimum-2-phase recipe, ONE barrier):
//     issue B gld_lds(t+1,nxt) + A fp32 loads(t+1) -> regs
//     ds_read cur frags + 32 MFMA (compiler fine-schedules lgkmcnt)
//     convert + swizzled ds_write A(t+1) -> nxt (implicit vmcnt wait on A regs
//       drains the older B glds too, FIFO)
//     __syncthreads()
//   Swizzle invariant both sides: phys k-chunk = logical ^ (row&7).
//   Grid 2048: 4 nt-siblings of an m-tile on the same XCD (A-panel L2 reuse).
//   Epilogue: tanh(acc + dp) * Wo, h-reduce -> parts[nt][b][s], nt in {0..3}.
__global__ __launch_bounds__(256, 2) void scores_gemm_kernel(
    const float* __restrict__ enc, const unsigned short* __restrict__ WeTcB,
    const float* __restrict__ Wo, const float* __restrict__ dp,
    float* __restrict__ parts) {
    __shared__ unsigned short sA[2][BM * BK];  // 2 x 16 KB
    __shared__ unsigned short sB[2][BN * BK];  // 2 x 16 KB
    __shared__ float sRed[2][BM];              // 1 KB

    int tid = threadIdx.x;
    int w = tid >> 6, l = tid & 63;
    int l16 = l & 15, quad = l >> 4;
    int wm = w & 1, wn = w >> 1;
    int lrow = l >> 3, lcp = l & 7;

    int bid = blockIdx.x;
    int xcd = bid & 7;
    int sq = bid >> 3;
    int nt = sq & 3;                      // 4 nt-siblings share an XCD
    int mt = ((sq >> 2) << 3) + xcd;      // [0,512)
    size_t m0 = (size_t)mt * BM;
    int n0 = nt * BN;
    int b = mt >> 5;

    // A source: lane covers rows m0 + w*8+lrow + {0,32,64,96}, fp32 cols
    // lcp*8..+8 of each k-tile.  LDS dest chunk = lcp ^ lrow.
    const float* gA = enc + (m0 + (size_t)(w * 8 + lrow)) * E_ + lcp * 8;
    const unsigned short* gB = WeTcB + (size_t)n0 * BK + (w * 8) * BK + l * 8;
    int awOff = (w * 8 + lrow) * BK + ((lcp ^ lrow) << 3);  // elems
    unsigned short* sBb0 = &sB[0][(w * 8) * BK];
    unsigned short* sBb1 = &sB[1][(w * 8) * BK];

#define STAGE_B(bb, tt) do {                                                   \
        const unsigned short* _s = gB + (size_t)(tt) * (H_ * BK);              \
        unsigned short* _d = (bb) ? sBb1 : sBb0;                               \
        _Pragma("unroll")                                                      \
        for (int i = 0; i < 4; ++i) GLD16(_s + i * 32 * BK, _d + i * 32 * BK); \
    } while (0)
#define ISSUE_A(tt) do {                                                       \
        const float* _p = gA + (tt) * BK;                                      \
        _Pragma("unroll")                                                      \
        for (int g = 0; g < 4; ++g) {                                          \
            av[2 * g]     = *(const float4*)(_p + (size_t)(g * 32) * E_);      \
            av[2 * g + 1] = *(const float4*)(_p + (size_t)(g * 32) * E_ + 4);  \
        }                                                                      \
    } while (0)
#define WRITE_A(bb) do {                                                       \
        _Pragma("unroll")                                                      \
        for (int g = 0; g < 4; ++g) {                                          \
            u16x8 _u;                                                          \
            _u[0] = f2bf(av[2 * g].x);     _u[1] = f2bf(av[2 * g].y);          \
            _u[2] = f2bf(av[2 * g].z);     _u[3] = f2bf(av[2 * g].w);          \
            _u[4] = f2bf(av[2 * g + 1].x); _u[5] = f2bf(av[2 * g + 1].y);      \
            _u[6] = f2bf(av[2 * g + 1].z); _u[7] = f2bf(av[2 * g + 1].w);      \
            *(u16x8*)(&sA[bb][awOff + g * 32 * BK]) = _u;                      \
        }                                                                      \
    } while (0)

    f32x4 acc[4][4];
#pragma unroll
    for (int i = 0; i < 4; ++i)
#pragma unroll
        for (int j = 0; j < 4; ++j) acc[i][j] = (f32x4)0.f;

    int arow = (wm * 64 + l16) * BK;
    int brow = (wn * 64 + l16) * BK;
    int sw = l16 & 7;

    float4 av[8];
    // Prologue: tile 0 into buf0.
    STAGE_B(0, 0);
    ISSUE_A(0);
    WRITE_A(0);  // compiler's vmcnt wait for av also drains the older B glds
    __syncthreads();

    for (int t = 0; t < NCHUNK; ++t) {
        int cur = t & 1, nxt = cur ^ 1;
        const unsigned short* sAc = sA[cur];
        const unsigned short* sBc = sB[cur];

        if (t + 1 < NCHUNK) {
            STAGE_B(nxt, t + 1);
            ISSUE_A(t + 1);
        }
#pragma unroll
        for (int half = 0; half < 2; ++half) {
            int koff = (((half * 4 + quad) ^ sw) << 3);
            bf16x8 aR[4], bR[4];
#pragma unroll
            for (int i = 0; i < 4; ++i)
                aR[i] = *(const bf16x8*)(sAc + arow + i * 16 * BK + koff);
#pragma unroll
            for (int j = 0; j < 4; ++j)
                bR[j] = *(const bf16x8*)(sBc + brow + j * 16 * BK + koff);
#pragma unroll
            for (int i = 0; i < 4; ++i)
#pragma unroll
                for (int j = 0; j < 4; ++j)
                    acc[i][j] = __builtin_amdgcn_mfma_f32_16x16x32_bf16(
                        aR[i], bR[j], acc[i][j], 0, 0, 0);
        }
        if (t + 1 < NCHUNK) WRITE_A(nxt);
        __syncthreads();  // drains vmcnt/lgkmcnt; one barrier per K-tile
    }
#undef STAGE_B
#undef ISSUE_A
#undef WRITE_A

    // Epilogue: tanh(acc + dp) * Wo, partial reduce over this block's 128 h.
    float dpv[4], wov[4];
    const float* dpb = dp + b * H_;
#pragma unroll
    for (int j = 0; j < 4; ++j) {
        int h = n0 + wn * 64 + j * 16 + l16;
        dpv[j] = dpb[h];
        wov[j] = Wo[h];
    }
#pragma unroll
    for (int i = 0; i < 4; ++i)
#pragma unroll
        for (int r = 0; r < 4; ++r) {
            float s = 0.f;
#pragma unroll
            for (int j = 0; j < 4; ++j) {
                float x = acc[i][j][r] + dpv[j];
                float e = __expf(2.f * x);
                s += (1.f - 2.f / (e + 1.f)) * wov[j];
            }
            s += __shfl_xor(s, 1, 64);
            s += __shfl_xor(s, 2, 64);
            s += __shfl_xor(s, 4, 64);
            s += __shfl_xor(s, 8, 64);
            if (l16 == 0) sRed[wn][wm * 64 + i * 16 + quad * 4 + r] = s;
        }
    __syncthreads();
    if (tid < BM) {
        int s_in = (int)(m0 & (S_ - 1)) + tid;
        parts[(size_t)(nt * B_ + b) * S_ + s_in] = sRed[0][tid] + sRed[1][tid];
    }
}

// Row softmax stats only: stats[b] = (max, sumexp) over summed 4-slab scores.
__global__ __launch_bounds__(256) void stats_kernel(const float* __restrict__ parts,
                                                    float2* __restrict__ stats) {
    int b = blockIdx.x, tid = threadIdx.x;
    const float4* p0 = (const float4*)(parts + (size_t)(0 * B_ + b) * S_);
    const float4* p1 = (const float4*)(parts + (size_t)(1 * B_ + b) * S_);
    const float4* p2 = (const float4*)(parts + (size_t)(2 * B_ + b) * S_);
    const float4* p3 = (const float4*)(parts + (size_t)(3 * B_ + b) * S_);
    float4 v[4];
    float m = -1e30f;
#pragma unroll
    for (int i = 0; i < 4; ++i) {
        int idx = i * 256 + tid;
        float4 a0 = p0[idx], a1 = p1[idx], a2 = p2[idx], a3 = p3[idx];
        v[i].x = a0.x + a1.x + a2.x + a3.x;
        v[i].y = a0.y + a1.y + a2.y + a3.y;
        v[i].z = a0.z + a1.z + a2.z + a3.z;
        v[i].w = a0.w + a1.w + a2.w + a3.w;
        m = fmaxf(m, fmaxf(fmaxf(v[i].x, v[i].y), fmaxf(v[i].z, v[i].w)));
    }
    for (int off = 32; off; off >>= 1) m = fmaxf(m, __shfl_xor(m, off, 64));
    __shared__ float redm[4];
    __shared__ float reds[4];
    if ((tid & 63) == 0) redm[tid >> 6] = m;
    __syncthreads();
    m = fmaxf(fmaxf(redm[0], redm[1]), fmaxf(redm[2], redm[3]));
    float s = 0.f;
#pragma unroll
    for (int i = 0; i < 4; ++i) {
        s += __expf(v[i].x - m) + __expf(v[i].y - m);
        s += __expf(v[i].z - m) + __expf(v[i].w - m);
    }
    for (int off = 32; off; off >>= 1) s += __shfl_xor(s, off, 64);
    if ((tid & 63) == 0) reds[tid >> 6] = s;
    __syncthreads();
    if (tid == 0) {
        stats[b] = make_float2(m, reds[0] + reds[1] + reds[2] + reds[3]);
    }
}

// ctx partials straight from enc fp32, weights exp(sc - m) from 4 slabs.
__global__ __launch_bounds__(256) void ctx_partial_f32(
    const float* __restrict__ enc, const float* __restrict__ parts,
    const float2* __restrict__ stats, float* __restrict__ part) {
    int b = blockIdx.x >> 5;
    int c = blockIdx.x & 31;
    int s0 = c * 128;
    int tid = threadIdx.x;
    __shared__ float w[128];
    if (tid < 128) {
        size_t idx = (size_t)b * S_ + s0 + tid;
        float x = parts[idx] + parts[(size_t)B_ * S_ + idx] +
                  parts[(size_t)(2 * B_) * S_ + idx] + parts[(size_t)(3 * B_) * S_ + idx];
        w[tid] = __expf(x - stats[b].x);
    }
    __syncthreads();
    int e8 = (tid & 127) * 8;
    int sh = tid >> 7;
    const float* base = enc + ((size_t)b * S_ + s0 + sh * 64) * E_ + e8;
    const float* wp = w + sh * 64;
    float acc[8];
#pragma unroll
    for (int t = 0; t < 8; ++t) acc[t] = 0.f;
    for (int s = 0; s < 64; s += 4) {
        float4 v0[4], v1[4];
#pragma unroll
        for (int u = 0; u < 4; ++u) {
            v0[u] = *(const float4*)(base + (size_t)(s + u) * E_);
            v1[u] = *(const float4*)(base + (size_t)(s + u) * E_ + 4);
        }
#pragma unroll
        for (int u = 0; u < 4; ++u) {
            float ws = wp[s + u];
            acc[0] = fmaf(ws, v0[u].x, acc[0]);
            acc[1] = fmaf(ws, v0[u].y, acc[1]);
            acc[2] = fmaf(ws, v0[u].z, acc[2]);
            acc[3] = fmaf(ws, v0[u].w, acc[3]);
            acc[4] = fmaf(ws, v1[u].x, acc[4]);
            acc[5] = fmaf(ws, v1[u].y, acc[5]);
            acc[6] = fmaf(ws, v1[u].z, acc[6]);
            acc[7] = fmaf(ws, v1[u].w, acc[7]);
        }
    }
    float* po = part + ((size_t)(b * 64 + c * 2 + sh)) * E_ + e8;
    *(float4*)(po) = make_float4(acc[0], acc[1], acc[2], acc[3]);
    *(float4*)(po + 4) = make_float4(acc[4], acc[5], acc[6], acc[7]);
}

__global__ __launch_bounds__(256) void ctx_reduce(const float* __restrict__ part,
                                                  const float2* __restrict__ stats,
                                                  float* __restrict__ out) {
    int idx = blockIdx.x * 256 + threadIdx.x;  // 16*1024
    int b = idx >> 10;
    int e = idx & 1023;
    const float* p = part + (size_t)b * 64 * E_ + e;
    float s0 = 0.f, s1 = 0.f, s2 = 0.f, s3 = 0.f;
    for (int c = 0; c < 64; c += 4) {
        s0 += p[(size_t)(c + 0) * E_];
        s1 += p[(size_t)(c + 1) * E_];
        s2 += p[(size_t)(c + 2) * E_];
        s3 += p[(size_t)(c + 3) * E_];
    }
    out[idx] = ((s0 + s1) + (s2 + s3)) * (1.f / stats[b].y);
}

extern "C" void kernel_launch(void* const* d_in, const int* in_sizes, int n_in,
                              void* d_out, int out_size, void* d_ws, size_t ws_size,
                              hipStream_t stream) {
    const float* enc = (const float*)d_in[0];  // [16,4096,1024]
    const float* dec = (const float*)d_in[1];  // [16,1024]
    const float* We  = (const float*)d_in[2];  // [1024,512]
    const float* be  = (const float*)d_in[3];  // [512]
    const float* Wd  = (const float*)d_in[4];  // [1024,512]
    const float* bd  = (const float*)d_in[5];  // [512]
    const float* Wo  = (const float*)d_in[6];  // [512,1]
    float* out = (float*)d_out;                // [16,1024]

    char* wsp = (char*)d_ws;
    unsigned short* WeTcB = (unsigned short*)wsp;              // 1 MiB
    float* dp = (float*)(wsp + (1 << 20));                     // 32 KiB
    float2* stats = (float2*)(wsp + (1 << 20) + (32 << 10));   // 128 B
    float* parts = (float*)(wsp + (1 << 20) + (64 << 10));     // 1 MiB (4 slabs)
    float* part = (float*)(wsp + (4 << 20));                   // 4 MiB

    prep_kernel<<<192, 256, 0, stream>>>(We, dec, Wd, bd, be, WeTcB, dp);
    scores_gemm_kernel<<<(B_ * S_ / BM) * (H_ / BN), 256, 0, stream>>>(
        enc, WeTcB, Wo, dp, parts);
    stats_kernel<<<B_, 256, 0, stream>>>(parts, stats);
    ctx_partial_f32<<<B_ * 32, 256, 0, stream>>>(enc, parts, stats, part);
    ctx_reduce<<<B_ * E_ / 256, 256, 0, stream>>>(part, stats, out);
}

// Round 5
// 490.904 us; speedup vs baseline: 1.1377x; 1.1377x over previous
//
#include <hip/hip_runtime.h>
#include <hip/hip_bf16.h>
#include <math.h>

#define B_ 16
#define S_ 4096
#define E_ 1024
#define H_ 512

#define BM 128
#define BN 256
#define BK 64
#define NCHUNK (E_ / BK)  // 16

typedef short bf16x8 __attribute__((ext_vector_type(8)));
typedef unsigned short u16x8 __attribute__((ext_vector_type(8)));
typedef float f32x4 __attribute__((ext_vector_type(4)));

__device__ inline unsigned short f2bf(float x) {
    __hip_bfloat16 h = __float2bfloat16(x);
    return *(unsigned short*)&h;
}
__device__ inline float bf2f(unsigned short u) {
    unsigned int x = ((unsigned int)u) << 16;
    float f;
    __builtin_memcpy(&f, &x, 4);
    return f;
}
__device__ __forceinline__ void gld16(const unsigned short* g, unsigned short* l) {
    __builtin_amdgcn_global_load_lds(
        (const __attribute__((address_space(1))) void*)g,
        (__attribute__((address_space(3))) void*)l, 16, 0, 0);
}

// One launch, three jobs (R0-proven structure):
//  blocks 0..63    : We -> WeTcB bf16, swizzled-chunk layout:
//                    WeTcB[c*32768 + n*64 + cp*8 + j] = We[k][n],
//                    k = c*64 + (cp ^ (n&7))*8 + j   (bank-conflict-free frags)
//  blocks 64..191  : dp[b][h] = dec[b,:].Wd[:,h] + bd[h] + be[h]
//  blocks 192..    : enc fp32 -> encB bf16 (row-major), 16 elems/thread
__global__ __launch_bounds__(256) void prep_conv_kernel(
    const float* __restrict__ enc, const float* __restrict__ We,
    const float* __restrict__ dec, const float* __restrict__ Wd,
    const float* __restrict__ bd, const float* __restrict__ be,
    unsigned short* __restrict__ WeTcB, float* __restrict__ dp,
    unsigned short* __restrict__ encB) {
    __shared__ float red[4][64];
    int bid = blockIdx.x, t = threadIdx.x;
    if (bid < 64) {
        int c = bid >> 2, n0t = (bid & 3) * 128;
#pragma unroll 4
        for (int it = 0; it < 32; ++it) {
            int o = it * 256 + t;
            int n_rel = o >> 6, within = o & 63;
            int cp = within >> 3, j = within & 7;
            int n = n0t + n_rel;
            int k = c * 64 + ((cp ^ (n & 7)) << 3) + j;
            WeTcB[c * 32768 + n * 64 + within] = f2bf(We[(size_t)k * H_ + n]);
        }
    } else if (bid < 192) {
        int id = bid - 64;
        int b = id >> 3, hc = id & 7;
        int h = hc * 64 + (t & 63);
        int ec = t >> 6;
        const float* dr = dec + b * E_ + ec * 256;
        const float* wp = Wd + (size_t)(ec * 256) * H_ + h;
        float acc = 0.f;
#pragma unroll 8
        for (int e = 0; e < 256; ++e) acc = fmaf(dr[e], wp[(size_t)e * H_], acc);
        red[ec][t & 63] = acc;
        __syncthreads();
        if (t < 64) {
            int hh = hc * 64 + t;
            dp[b * H_ + hh] = red[0][t] + red[1][t] + red[2][t] + red[3][t] + bd[hh] + be[hh];
        }
    } else {
        size_t base = ((size_t)(bid - 192) * 256 + t) * 16;
        const float* ep = enc + base;
        unsigned short* op = encB + base;
        float4 v0 = *(const float4*)(ep);
        float4 v1 = *(const float4*)(ep + 4);
        float4 v2 = *(const float4*)(ep + 8);
        float4 v3 = *(const float4*)(ep + 12);
        u16x8 u0, u1;
        u0[0] = f2bf(v0.x); u0[1] = f2bf(v0.y); u0[2] = f2bf(v0.z); u0[3] = f2bf(v0.w);
        u0[4] = f2bf(v1.x); u0[5] = f2bf(v1.y); u0[6] = f2bf(v1.z); u0[7] = f2bf(v1.w);
        u1[0] = f2bf(v2.x); u1[1] = f2bf(v2.y); u1[2] = f2bf(v2.z); u1[3] = f2bf(v2.w);
        u1[4] = f2bf(v3.x); u1[5] = f2bf(v3.y); u1[6] = f2bf(v3.z); u1[7] = f2bf(v3.w);
        *(u16x8*)(op) = u0;
        *(u16x8*)(op + 8) = u1;
    }
}

// 128x256x64 GEMM, 4 waves (2m x 2n), per-wave 64m x 128n = 4x8 frags.
//   Rationale (R0-R3 evidence): time tracks A-operand bytes through the cache
//   hierarchy (~4.2 TB/s effective), so BN=256 halves nt-sibling A re-reads
//   (logical A 512 -> 256 MiB) vs R0's BN=128.  Keep R0's proven pieces: bf16
//   A from encB, gld_lds staging both operands, XOR chunk swizzle (phys =
//   logical ^ (row&7)) realized via pre-swizzled global addresses, 2-phase
//   K-loop.  LDS 65 KB -> 2 blocks/CU.  B is single-buffered: stage B(t+1)
//   after a raw barrier (all B-reads of tile t done), then vmcnt(0)+barrier.
//   A(t+1) double-buffered, staged at tile top (latency hidden under MFMA).
__global__ __launch_bounds__(256, 2) void scores_gemm_kernel(
    const unsigned short* __restrict__ encB, const unsigned short* __restrict__ WeTcB,
    const float* __restrict__ Wo, const float* __restrict__ dp,
    float* __restrict__ parts) {
    __shared__ unsigned short sA[2][BM * BK];  // 2 x 16 KB
    __shared__ unsigned short sB[BN * BK];     // 32 KB (single buffer)
    __shared__ float sRed[2][BM];              // 1 KB

    int tid = threadIdx.x;
    int w = tid >> 6, l = tid & 63;
    int l16 = l & 15, quad = l >> 4;
    int wm = w & 1, wn = w >> 1;
    int lrow = l >> 3, lcp = l & 7;

    int bid = blockIdx.x;
    int xcd = bid & 7;
    int sq = bid >> 3;
    int nt = sq & 1;                      // 2 nt-siblings share an XCD
    int mt = ((sq >> 1) << 3) + xcd;      // [0,512)
    size_t m0 = (size_t)mt * BM;
    int n0 = nt * BN;
    int b = mt >> 5;

    // staging lane constants (R0 pattern): lane gathers logical k-chunk
    // (lcp ^ lrow) so linear LDS leaves logical chunk q at phys q ^ (row&7).
    const unsigned short* gA = encB + (m0 + (size_t)(w * 8 + lrow)) * E_ + (lcp ^ lrow) * 8;
    const unsigned short* gB = WeTcB + (size_t)n0 * BK + (w * 8) * BK + l * 8;
    unsigned short* sAb0 = &sA[0][(w * 8) * BK];
    unsigned short* sAb1 = &sA[1][(w * 8) * BK];
    unsigned short* sBb = &sB[(w * 8) * BK];

#define STAGE_A(bb, tt) do {                                                   \
        const unsigned short* _s = gA + (tt) * BK;                             \
        unsigned short* _d = (bb) ? sAb1 : sAb0;                               \
        _Pragma("unroll")                                                      \
        for (int i = 0; i < 4; ++i)                                            \
            gld16(_s + (size_t)(i * 32) * E_, _d + i * 32 * BK);               \
    } while (0)
#define STAGE_B(tt) do {                                                       \
        const unsigned short* _s = gB + (size_t)(tt) * (H_ * BK);              \
        _Pragma("unroll")                                                      \
        for (int i = 0; i < 8; ++i) gld16(_s + i * 32 * BK, sBb + i * 32 * BK);\
    } while (0)

    f32x4 acc[4][8];
#pragma unroll
    for (int i = 0; i < 4; ++i)
#pragma unroll
        for (int j = 0; j < 8; ++j) acc[i][j] = (f32x4)0.f;

    int arow = (wm * 64 + l16) * BK;
    int brow = (wn * 128 + l16) * BK;
    int sw = l16 & 7;

    // Prologue: tile 0 (A buf0 + B), drain, barrier.
    STAGE_B(0);
    STAGE_A(0, 0);
    asm volatile("s_waitcnt vmcnt(0) lgkmcnt(0)" ::: "memory");
    __builtin_amdgcn_s_barrier();
    asm volatile("" ::: "memory");

    for (int t = 0; t < NCHUNK; ++t) {
        int cur = t & 1, nxt = cur ^ 1;
        const unsigned short* sAc = sA[cur];

        if (t + 1 < NCHUNK) STAGE_A(nxt, t + 1);  // dbuf: hidden under MFMA

        __builtin_amdgcn_s_setprio(1);
#pragma unroll
        for (int half = 0; half < 2; ++half) {
            int koff = (((half * 4 + quad) ^ sw) << 3);
            bf16x8 aR[4], bR[8];
#pragma unroll
            for (int i = 0; i < 4; ++i)
                aR[i] = *(const bf16x8*)(sAc + arow + i * 16 * BK + koff);
#pragma unroll
            for (int j = 0; j < 8; ++j)
                bR[j] = *(const bf16x8*)(sB + brow + j * 16 * BK + koff);
#pragma unroll
            for (int i = 0; i < 4; ++i)
#pragma unroll
                for (int j = 0; j < 8; ++j)
                    acc[i][j] = __builtin_amdgcn_mfma_f32_16x16x32_bf16(
                        aR[i], bR[j], acc[i][j], 0, 0, 0);
        }
        __builtin_amdgcn_s_setprio(0);

        if (t + 1 < NCHUNK) {
            // all waves done reading sB of tile t (ds_reads consumed; lgkm=0)
            asm volatile("s_waitcnt lgkmcnt(0)" ::: "memory");
            __builtin_amdgcn_s_barrier();
            asm volatile("" ::: "memory");
            STAGE_B(t + 1);
            asm volatile("s_waitcnt vmcnt(0)" ::: "memory");  // B (and A) landed
            __builtin_amdgcn_s_barrier();
            asm volatile("" ::: "memory");
        }
    }
#undef STAGE_A
#undef STAGE_B

    // Epilogue: tanh(acc + dp) * Wo, partial reduce over this block's 256 h.
    float dpv[8], wov[8];
    const float* dpb = dp + b * H_;
#pragma unroll
    for (int j = 0; j < 8; ++j) {
        int h = n0 + wn * 128 + j * 16 + l16;
        dpv[j] = dpb[h];
        wov[j] = Wo[h];
    }
#pragma unroll
    for (int i = 0; i < 4; ++i)
#pragma unroll
        for (int r = 0; r < 4; ++r) {
            float s = 0.f;
#pragma unroll
            for (int j = 0; j < 8; ++j) {
                float x = acc[i][j][r] + dpv[j];
                float e = __expf(2.f * x);
                s += (1.f - 2.f / (e + 1.f)) * wov[j];
            }
            s += __shfl_xor(s, 1, 64);
            s += __shfl_xor(s, 2, 64);
            s += __shfl_xor(s, 4, 64);
            s += __shfl_xor(s, 8, 64);
            if (l16 == 0) sRed[wn][wm * 64 + i * 16 + quad * 4 + r] = s;
        }
    __syncthreads();
    if (tid < BM) {
        int s_in = (int)(m0 & (S_ - 1)) + tid;
        parts[(size_t)(nt * B_ + b) * S_ + s_in] = sRed[0][tid] + sRed[1][tid];
    }
}

// Row softmax stats only: stats[b] = (max, sumexp) over summed 2-slab scores.
__global__ __launch_bounds__(256) void stats_kernel(const float* __restrict__ parts,
                                                    float2* __restrict__ stats) {
    int b = blockIdx.x, tid = threadIdx.x;
    const float4* p0 = (const float4*)(parts + (size_t)(0 * B_ + b) * S_);
    const float4* p1 = (const float4*)(parts + (size_t)(1 * B_ + b) * S_);
    float4 v[4];
    float m = -1e30f;
#pragma unroll
    for (int i = 0; i < 4; ++i) {
        int idx = i * 256 + tid;
        float4 a0 = p0[idx], a1 = p1[idx];
        v[i].x = a0.x + a1.x;
        v[i].y = a0.y + a1.y;
        v[i].z = a0.z + a1.z;
        v[i].w = a0.w + a1.w;
        m = fmaxf(m, fmaxf(fmaxf(v[i].x, v[i].y), fmaxf(v[i].z, v[i].w)));
    }
    for (int off = 32; off; off >>= 1) m = fmaxf(m, __shfl_xor(m, off, 64));
    __shared__ float redm[4];
    __shared__ float reds[4];
    if ((tid & 63) == 0) redm[tid >> 6] = m;
    __syncthreads();
    m = fmaxf(fmaxf(redm[0], redm[1]), fmaxf(redm[2], redm[3]));
    float s = 0.f;
#pragma unroll
    for (int i = 0; i < 4; ++i) {
        s += __expf(v[i].x - m) + __expf(v[i].y - m);
        s += __expf(v[i].z - m) + __expf(v[i].w - m);
    }
    for (int off = 32; off; off >>= 1) s += __shfl_xor(s, off, 64);
    if ((tid & 63) == 0) reds[tid >> 6] = s;
    __syncthreads();
    if (tid == 0) {
        stats[b] = make_float2(m, reds[0] + reds[1] + reds[2] + reds[3]);
    }
}

// ctx partials from bf16 enc copy, unnormalized weights exp(sc - m), 2 slabs.
__global__ __launch_bounds__(256) void ctx_partial_bf16(
    const unsigned short* __restrict__ encB, const float* __restrict__ parts,
    const float2* __restrict__ stats, float* __restrict__ part) {
    int b = blockIdx.x >> 5;
    int c = blockIdx.x & 31;
    int s0 = c * 128;
    int tid = threadIdx.x;
    __shared__ float w[128];
    if (tid < 128) {
        size_t idx = (size_t)b * S_ + s0 + tid;
        float x = parts[idx] + parts[(size_t)B_ * S_ + idx];
        w[tid] = __expf(x - stats[b].x);
    }
    __syncthreads();
    int e8 = (tid & 127) * 8;
    int sh = tid >> 7;
    const unsigned short* base = encB + ((size_t)b * S_ + s0 + sh * 64) * E_ + e8;
    const float* wp = w + sh * 64;
    float acc[8];
#pragma unroll
    for (int t = 0; t < 8; ++t) acc[t] = 0.f;
    for (int s = 0; s < 64; s += 8) {
        u16x8 v[8];
#pragma unroll
        for (int u = 0; u < 8; ++u) v[u] = *(const u16x8*)(base + (size_t)(s + u) * E_);
#pragma unroll
        for (int u = 0; u < 8; ++u) {
            float ws = wp[s + u];
#pragma unroll
            for (int t = 0; t < 8; ++t) acc[t] = fmaf(ws, bf2f(v[u][t]), acc[t]);
        }
    }
    float* po = part + ((size_t)(b * 64 + c * 2 + sh)) * E_ + e8;
    *(float4*)(po) = make_float4(acc[0], acc[1], acc[2], acc[3]);
    *(float4*)(po + 4) = make_float4(acc[4], acc[5], acc[6], acc[7]);
}

__global__ __launch_bounds__(256) void ctx_reduce(const float* __restrict__ part,
                                                  const float2* __restrict__ stats,
                                                  float* __restrict__ out) {
    int idx = blockIdx.x * 256 + threadIdx.x;  // 16*1024
    int b = idx >> 10;
    int e = idx & 1023;
    const float* p = part + (size_t)b * 64 * E_ + e;
    float s0 = 0.f, s1 = 0.f, s2 = 0.f, s3 = 0.f;
    for (int c = 0; c < 64; c += 4) {
        s0 += p[(size_t)(c + 0) * E_];
        s1 += p[(size_t)(c + 1) * E_];
        s2 += p[(size_t)(c + 2) * E_];
        s3 += p[(size_t)(c + 3) * E_];
    }
    out[idx] = ((s0 + s1) + (s2 + s3)) * (1.f / stats[b].y);
}

extern "C" void kernel_launch(void* const* d_in, const int* in_sizes, int n_in,
                              void* d_out, int out_size, void* d_ws, size_t ws_size,
                              hipStream_t stream) {
    const float* enc = (const float*)d_in[0];  // [16,4096,1024]
    const float* dec = (const float*)d_in[1];  // [16,1024]
    const float* We  = (const float*)d_in[2];  // [1024,512]
    const float* be  = (const float*)d_in[3];  // [512]
    const float* Wd  = (const float*)d_in[4];  // [1024,512]
    const float* bd  = (const float*)d_in[5];  // [512]
    const float* Wo  = (const float*)d_in[6];  // [512,1]
    float* out = (float*)d_out;                // [16,1024]

    char* wsp = (char*)d_ws;
    unsigned short* WeTcB = (unsigned short*)wsp;              // 1 MiB
    float* dp = (float*)(wsp + (1 << 20));                     // 32 KiB
    float2* stats = (float2*)(wsp + (1 << 20) + (32 << 10));   // 128 B
    float* parts = (float*)(wsp + (1 << 20) + (64 << 10));     // 512 KiB (2 slabs)
    float* part = (float*)(wsp + (4 << 20));                   // 4 MiB
    unsigned short* encB = (unsigned short*)(wsp + (8 << 20)); // 128 MiB

    prep_conv_kernel<<<192 + 16384, 256, 0, stream>>>(enc, We, dec, Wd, bd, be,
                                                      WeTcB, dp, encB);
    scores_gemm_kernel<<<(B_ * S_ / BM) * (H_ / BN), 256, 0, stream>>>(
        encB, WeTcB, Wo, dp, parts);
    stats_kernel<<<B_, 256, 0, stream>>>(parts, stats);
    ctx_partial_bf16<<<B_ * 32, 256, 0, stream>>>(encB, parts, stats, part);
    ctx_reduce<<<B_ * E_ / 256, 256, 0, stream>>>(part, stats, out);
}